// Round 2
// baseline (241.699 us; speedup 1.0000x reference)
//
#include <hip/hip_runtime.h>
#include <hip/hip_bf16.h>
#include <hip/hip_fp16.h>

// ============================================================================
// GCN forward. CSR-by-dst via fixed-capacity bucketed counting sort; fused
// gather+dense layer kernels, 8 lanes/node with OCTET-COOPERATIVE ROW-SPLIT
// gathers:
//   - gather: all 8 lanes of an octet load the SAME edge's row, lane l takes
//     bytes [8l, 8l+8). One coalesced instruction per edge (8 lines/wave-inst
//     instead of 64), and each lane ends up owning a 4-dim slice of the
//     aggregated vector -- no reduce-scatter shfl cascade needed, and the
//     accumulator footprint drops from 18-32 VGPRs to 2-4.
//   - dense: packed-fp16 weights in LDS + v_dot2_f32_f16 (f32 accumulate).
//       * L12 stage-1 (18->64): 9-shfl allgather of packed k-pairs, then
//         9 k-pair dot2s, j-split 8.
//       * L12 stage-2 (64->32): f-split 8, octet shfl exchange, b128 LDS.
//       * L3 (32->16): lane owns k[4l..4l+4) directly from row-split gather.
//       * L4 (16->2):  lane owns k[2l..2l+2) directly from row-split gather.
//   - xs rows padded to 32 halves (64B, zero-filled) so row-split is uniform
//     and every gather is exactly one 64B sector.
// Algebra: A_hat(xW) = (A_hat x)W, normalization factored as
//   out[d] = dinv[d] * ( sum_{s in N(d)} hs[s] + hs[d] ) + b,  hs = h*dinv[row]
// hs tables fp16 (fp32 accumulation): xs=6.4MB, h2s=6.4MB, h3s=3.2MB.
// ============================================================================

#define NBUCK_SHIFT 8            // 256 nodes per bucket
#define CAP         8192         // bucket capacity (avg 4096, sigma ~64)
#define PART_CHUNK  2048         // edges per partition block (256 thr x 8)

// ---------------- fp16 pair helpers ----------------
typedef _Float16 h2vec __attribute__((ext_vector_type(2)));

__device__ inline unsigned int pack2(float a, float b) {
    __half2 h = __floats2half2_rn(a, b);
    return *reinterpret_cast<unsigned int*>(&h);
}

__device__ inline float2 h2f(unsigned int u) {
    __half2 h = *reinterpret_cast<__half2*>(&u);
    return __half22float2(h);
}

__device__ inline float dot2f(unsigned int w, unsigned int h, float c) {
#if defined(__has_builtin) && __has_builtin(__builtin_amdgcn_fdot2)
    union U { unsigned int u; h2vec v; };
    U uw, uh; uw.u = w; uh.u = h;
    return __builtin_amdgcn_fdot2(uh.v, uw.v, c, false);
#else
    float2 wf = h2f(w);
    float2 hf = h2f(h);
    return fmaf(hf.x, wf.x, fmaf(hf.y, wf.y, c));
#endif
}

// ---------------- init per-bucket cursors to fixed bases ----------------
__global__ void init_gcur_kernel(int* __restrict__ gcur, int nbuck) {
    int i = threadIdx.x;
    if (i < nbuck) gcur[i] = i * CAP;
}

// ---------------- partition edges into fixed-capacity buckets ----------------
// staged word: (src << 8) | (dst & 255)
__global__ __launch_bounds__(256) void partition_kernel(const int* __restrict__ src,
                                                        const int* __restrict__ dst,
                                                        int* __restrict__ gcur,
                                                        unsigned int* __restrict__ bucketed,
                                                        int n_edges, int nbuck) {
    __shared__ int cnt[512];
    __shared__ int base[512];
    const int t = threadIdx.x;
    for (int i = t; i < 512; i += 256) cnt[i] = 0;
    __syncthreads();
    long long start = (long long)blockIdx.x * PART_CHUNK;
    int sv[8], dv[8], bv[8];
#pragma unroll
    for (int k = 0; k < 8; ++k) {
        long long e = start + (long long)k * 256 + t;
        bool ok = e < n_edges;
        sv[k] = ok ? src[e] : 0;
        dv[k] = ok ? dst[e] : 0;
        bv[k] = ok ? (dv[k] >> NBUCK_SHIFT) : -1;
        if (ok) atomicAdd(&cnt[bv[k]], 1);
    }
    __syncthreads();
    for (int i = t; i < nbuck; i += 256) {
        int c = cnt[i];
        base[i] = c ? atomicAdd(&gcur[i], c) : 0;
    }
    __syncthreads();
    for (int i = t; i < 512; i += 256) cnt[i] = 0;   // reuse as running cursor
    __syncthreads();
#pragma unroll
    for (int k = 0; k < 8; ++k) {
        if (bv[k] >= 0) {
            int pos = base[bv[k]] + atomicAdd(&cnt[bv[k]], 1);
            bucketed[pos] = ((unsigned int)sv[k] << 8) | (unsigned int)(dv[k] & 255);
        }
    }
}

// ---------------- per-bucket CSR finalize + x scale/pad ----------------------
// ends=(beg,end), dinv, sorted_src placement, and xs = half(x*dinv) stride 32,
// zero-padded so row-split lanes read valid zeros.
__device__ inline float4 pack8_dev(const float* v) {
    float4 out;
    __half2* h2 = reinterpret_cast<__half2*>(&out);
#pragma unroll
    for (int j = 0; j < 4; ++j) h2[j] = __floats2half2_rn(v[2 * j], v[2 * j + 1]);
    return out;
}

__global__ __launch_bounds__(256) void csr_kernel(const unsigned int* __restrict__ bucketed,
                                                  const int* __restrict__ gcur,
                                                  const float* __restrict__ x,
                                                  int2* __restrict__ ends,
                                                  float* __restrict__ dinv,
                                                  int* __restrict__ sorted_src,
                                                  __half* __restrict__ xs,
                                                  int n) {
    __shared__ int ldeg[256];
    __shared__ int lscan[256];
    const int b = blockIdx.x;
    const int t = threadIdx.x;
    const int beg = b * CAP;
    const int end = gcur[b];                 // beg + count(bucket b)
    ldeg[t] = 0;
    __syncthreads();
    for (int e = beg + t; e < end; e += 256) {
        unsigned int p = bucketed[e];
        atomicAdd(&ldeg[p & 255u], 1);
    }
    __syncthreads();
    int v = ldeg[t];
    lscan[t] = v;
    __syncthreads();
    for (int off = 1; off < 256; off <<= 1) {
        int xv = (t >= off) ? lscan[t - off] : 0;
        __syncthreads();
        lscan[t] += xv;
        __syncthreads();
    }
    int excl = lscan[t] - v;                 // exclusive scan
    int node = (b << NBUCK_SHIFT) + t;
    float di = rsqrtf((float)v + 1.0f);      // +1 self-loop
    if (node < n) {
        ends[node] = make_int2(beg + excl, beg + excl + v);
        dinv[node] = di;
        // xs row = half(x * di), stride 32 halves, halves 18..31 zeroed
        const float* xr = x + (long long)node * 18;
        float vv[18];
#pragma unroll
        for (int k = 0; k < 18; ++k) vv[k] = xr[k] * di;
        float vt[8] = {vv[16], vv[17], 0.0f, 0.0f, 0.0f, 0.0f, 0.0f, 0.0f};
        float4* o = reinterpret_cast<float4*>(xs + (long long)node * 32);
        o[0] = pack8_dev(vv);
        o[1] = pack8_dev(vv + 8);
        o[2] = pack8_dev(vt);
        o[3] = make_float4(0.0f, 0.0f, 0.0f, 0.0f);
    }
    __syncthreads();
    lscan[t] = beg + excl;                   // reuse as placement cursor
    __syncthreads();
    for (int e = beg + t; e < end; e += 256) {
        unsigned int p = bucketed[e];
        int pos = atomicAdd(&lscan[p & 255u], 1);
        sorted_src[pos] = (int)(p >> 8);
    }
}

// ---------------- fused layer 1+2 (8 lanes/node, row-split gather) ----------
// gather: lane owns halves [4*l8, 4*l8+4) of the 32-half row; one uint2 per
// edge per lane (coalesced across octet). 9-shfl allgather of packed k-pairs
// -> 18->64 relu (j-split 8, dot2) -> 64->32 (f-split 8, octet shfl, dot2).
__global__ __launch_bounds__(256, 6) void layer12_kernel(
    const __half* __restrict__ xs, const float* __restrict__ dinv,
    const int* __restrict__ sorted_src, const int2* __restrict__ ends,
    const float* __restrict__ W1, const float* __restrict__ b1,
    const float* __restrict__ W2, __half* __restrict__ h2s, int n) {
    __shared__ unsigned int w1h[9 * 64];     // [kp][j] pairs of x-dim
    __shared__ float sB1[64];
    __shared__ unsigned int w2h[32 * 32];    // [jp][f] pairs of hidden-dim
    for (int i = threadIdx.x; i < 9 * 64; i += 256) {
        int kp = i >> 6, j = i & 63;
        w1h[i] = pack2(W1[(2 * kp) * 64 + j], W1[(2 * kp + 1) * 64 + j]);
    }
    for (int i = threadIdx.x; i < 64; i += 256) sB1[i] = b1[i];
    for (int i = threadIdx.x; i < 32 * 32; i += 256) {
        int jp = i >> 5, f = i & 31;
        w2h[i] = pack2(W2[(2 * jp) * 32 + f], W2[(2 * jp + 1) * 32 + f]);
    }
    __syncthreads();

    long long gt = (long long)blockIdx.x * 256 + threadIdx.x;
    int node = (int)(gt >> 3);
    int l8   = (int)(gt & 7);
    if (node >= n) return;
    int2 be = ends[node];
    float di = dinv[node];

    // ---- row-split gather: lane l8 accumulates halves [4*l8, 4*l8+4) ----
    float a0 = 0.0f, a1 = 0.0f, a2 = 0.0f, a3 = 0.0f;
    {   // self row (all lanes)
        uint2 rv = *reinterpret_cast<const uint2*>(xs + ((long long)node << 5) + (l8 << 2));
        float2 x0 = h2f(rv.x), x1 = h2f(rv.y);
        a0 += x0.x; a1 += x0.y; a2 += x1.x; a3 += x1.y;
    }
    for (int e = be.x; e < be.y; ++e) {
        int s = sorted_src[e];
        uint2 rv = *reinterpret_cast<const uint2*>(xs + ((long long)s << 5) + (l8 << 2));
        float2 x0 = h2f(rv.x), x1 = h2f(rv.y);
        a0 += x0.x; a1 += x0.y; a2 += x1.x; a3 += x1.y;
    }
    // lane l8 owns k-pairs (2*l8, 2*l8+1); allgather the 9 live pairs
    unsigned int apl0 = pack2(a0, a1);
    unsigned int apl1 = pack2(a2, a3);
    unsigned int ap[9];
#pragma unroll
    for (int q = 0; q < 9; ++q)
        ap[q] = (unsigned int)__shfl((int)((q & 1) ? apl1 : apl0), q >> 1, 8);

    // ---- stage 1: hidden slice j0 = l8*8, dot2 over 9 k-pairs ----
    const int j0 = l8 * 8;
    float raw[8];
#pragma unroll
    for (int jj = 0; jj < 8; ++jj) raw[jj] = 0.0f;
#pragma unroll
    for (int kp = 0; kp < 9; ++kp) {
        const uint4* wv = reinterpret_cast<const uint4*>(&w1h[kp * 64 + j0]);
        uint4 wa = wv[0], wb = wv[1];
        unsigned int a = ap[kp];
        raw[0] = dot2f(wa.x, a, raw[0]); raw[1] = dot2f(wa.y, a, raw[1]);
        raw[2] = dot2f(wa.z, a, raw[2]); raw[3] = dot2f(wa.w, a, raw[3]);
        raw[4] = dot2f(wb.x, a, raw[4]); raw[5] = dot2f(wb.y, a, raw[5]);
        raw[6] = dot2f(wb.z, a, raw[6]); raw[7] = dot2f(wb.w, a, raw[7]);
    }
    unsigned int hpu[4];
#pragma unroll
    for (int q = 0; q < 4; ++q) {          // hid = relu(di*raw + b1), packed
        float h0 = fmaxf(fmaf(raw[2 * q],     di, sB1[j0 + 2 * q]),     0.0f);
        float h1 = fmaxf(fmaf(raw[2 * q + 1], di, sB1[j0 + 2 * q + 1]), 0.0f);
        hpu[q] = pack2(h0, h1);
    }

    // ---- stage 2: f-split (f0 = l8*4); hid pairs exchanged via octet shfl --
    float out[4] = {0.0f, 0.0f, 0.0f, 0.0f};
#pragma unroll
    for (int m = 0; m < 8; ++m) {
        const int lx = l8 ^ m;
#pragma unroll
        for (int q = 0; q < 4; ++q) {
            unsigned int hh = m ? (unsigned int)__shfl_xor(hpu[q], m) : hpu[q];
            const uint4 w = *reinterpret_cast<const uint4*>(&w2h[(lx * 4 + q) * 32 + l8 * 4]);
            out[0] = dot2f(w.x, hh, out[0]);
            out[1] = dot2f(w.y, hh, out[1]);
            out[2] = dot2f(w.z, hh, out[2]);
            out[3] = dot2f(w.w, hh, out[3]);
        }
    }
    union { float2 f2; __half2 h2[2]; } u;
    u.h2[0] = __floats2half2_rn(out[0] * di, out[1] * di);
    u.h2[1] = __floats2half2_rn(out[2] * di, out[3] * di);
    *reinterpret_cast<float2*>(h2s + (long long)node * 32 + l8 * 4) = u.f2;
}

// ---------------- fused layer 3 (8 lanes/node, row-split gather) ------------
// gather: lane owns k in [4*l8, 4*l8+4) directly (no reduce-scatter).
// -> relu(+b2) -> 32->16 f-split (f0=l8*2, dot2, octet shfl).
__global__ __launch_bounds__(256, 8) void layer3_kernel(
    const __half* __restrict__ h2s, const float* __restrict__ dinv,
    const int* __restrict__ sorted_src, const int2* __restrict__ ends,
    const float* __restrict__ b2, const float* __restrict__ W3,
    __half* __restrict__ h3s, int n) {
    __shared__ unsigned int w3h[16 * 16];    // [kp][f] pairs of k-dim
    __shared__ float sB2[32];
    {
        int i = threadIdx.x;
        if (i < 256) {
            int kp = i >> 4, f = i & 15;
            w3h[i] = pack2(W3[(2 * kp) * 16 + f], W3[(2 * kp + 1) * 16 + f]);
        }
    }
    for (int i = threadIdx.x; i < 32; i += 256) sB2[i] = b2[i];
    __syncthreads();

    long long gt = (long long)blockIdx.x * 256 + threadIdx.x;
    int node = (int)(gt >> 3);
    int l8   = (int)(gt & 7);
    if (node >= n) return;
    int2 be = ends[node];
    float di = dinv[node];

    float a0 = 0.0f, a1 = 0.0f, a2 = 0.0f, a3 = 0.0f;
    {   // self row
        uint2 rv = *reinterpret_cast<const uint2*>(h2s + ((long long)node << 5) + (l8 << 2));
        float2 x0 = h2f(rv.x), x1 = h2f(rv.y);
        a0 += x0.x; a1 += x0.y; a2 += x1.x; a3 += x1.y;
    }
    for (int e = be.x; e < be.y; ++e) {
        int s = sorted_src[e];
        uint2 rv = *reinterpret_cast<const uint2*>(h2s + ((long long)s << 5) + (l8 << 2));
        float2 x0 = h2f(rv.x), x1 = h2f(rv.y);
        a0 += x0.x; a1 += x0.y; a2 += x1.x; a3 += x1.y;
    }

    // ---- dense: relu'd k-pairs exchanged via octet shfl, dot2 ----
    const int k0 = l8 * 4;
    float v0 = fmaxf(fmaf(a0, di, sB2[k0 + 0]), 0.0f);
    float v1 = fmaxf(fmaf(a1, di, sB2[k0 + 1]), 0.0f);
    float v2 = fmaxf(fmaf(a2, di, sB2[k0 + 2]), 0.0f);
    float v3 = fmaxf(fmaf(a3, di, sB2[k0 + 3]), 0.0f);
    unsigned int vp[2] = { pack2(v0, v1), pack2(v2, v3) };
    float o0 = 0.0f, o1 = 0.0f;
#pragma unroll
    for (int m = 0; m < 8; ++m) {
        const int lx = l8 ^ m;
#pragma unroll
        for (int q = 0; q < 2; ++q) {
            unsigned int hh = m ? (unsigned int)__shfl_xor(vp[q], m) : vp[q];
            const uint2 w = *reinterpret_cast<const uint2*>(&w3h[(lx * 2 + q) * 16 + l8 * 2]);
            o0 = dot2f(w.x, hh, o0);
            o1 = dot2f(w.y, hh, o1);
        }
    }
    *reinterpret_cast<__half2*>(h3s + (long long)node * 16 + l8 * 2) =
        __floats2half2_rn(o0 * di, o1 * di);
}

// ---------------- fused layer 4 (8 lanes/node, row-split gather) -------------
// gather: lane owns k in [2*l8, 2*l8+2) directly. -> relu(+b3) -> 16->2.
__global__ __launch_bounds__(256, 8) void layer4_kernel(
    const __half* __restrict__ h3s, const float* __restrict__ dinv,
    const int* __restrict__ sorted_src, const int2* __restrict__ ends,
    const float* __restrict__ b3, const float* __restrict__ W4,
    __half* __restrict__ h4s, int n) {
    __shared__ float sW4[32];
    __shared__ float sB3[16];
    for (int i = threadIdx.x; i < 32; i += 256) sW4[i] = W4[i];
    for (int i = threadIdx.x; i < 16; i += 256) sB3[i] = b3[i];
    __syncthreads();

    long long gt = (long long)blockIdx.x * 256 + threadIdx.x;
    int node = (int)(gt >> 3);
    int l8   = (int)(gt & 7);
    if (node >= n) return;
    int2 be = ends[node];
    float di = dinv[node];

    float a0 = 0.0f, a1 = 0.0f;
    {   // self row
        unsigned int rv = *reinterpret_cast<const unsigned int*>(h3s + ((long long)node << 4) + (l8 << 1));
        float2 x0 = h2f(rv);
        a0 += x0.x; a1 += x0.y;
    }
    for (int e = be.x; e < be.y; ++e) {
        int s = sorted_src[e];
        unsigned int rv = *reinterpret_cast<const unsigned int*>(h3s + ((long long)s << 4) + (l8 << 1));
        float2 x0 = h2f(rv);
        a0 += x0.x; a1 += x0.y;
    }

    const int k0 = l8 * 2;
    float w0a = sW4[2 * k0],       w0b = sW4[2 * k0 + 1];
    float w1a = sW4[2 * (k0 + 1)], w1b = sW4[2 * (k0 + 1) + 1];
    float va = fmaxf(fmaf(a0, di, sB3[k0]),     0.0f);
    float vb = fmaxf(fmaf(a1, di, sB3[k0 + 1]), 0.0f);
    float o0 = fmaf(va, w0a, vb * w1a);
    float o1 = fmaf(va, w0b, vb * w1b);
    o0 += __shfl_xor(o0, 1); o0 += __shfl_xor(o0, 2); o0 += __shfl_xor(o0, 4);
    o1 += __shfl_xor(o1, 1); o1 += __shfl_xor(o1, 2); o1 += __shfl_xor(o1, 4);
    if (l8 == 0)
        *reinterpret_cast<__half2*>(h4s + 2LL * node) = __floats2half2_rn(o0 * di, o1 * di);
}

// ---------------- final: F=2 aggregation + log_softmax (8 lanes/node) --------
__global__ __launch_bounds__(256, 8) void agg2_lsm_kernel(
    const __half* __restrict__ hs, const float* __restrict__ dinv,
    const int* __restrict__ sorted_src, const int2* __restrict__ ends,
    const float* __restrict__ b, float* __restrict__ out, int n) {
    long long gt = (long long)blockIdx.x * 256 + threadIdx.x;
    int node = (int)(gt >> 3);
    int l8   = (int)(gt & 7);
    if (node >= n) return;
    int2 be = ends[node];
    float ax = 0.0f, ay = 0.0f;
    if (l8 == 7) {
        float2 r = __half22float2(*reinterpret_cast<const __half2*>(hs + 2LL * node));
        ax += r.x; ay += r.y;
    }
    for (int e = be.x + l8; e < be.y; e += 8) {
        int s = sorted_src[e];
        float2 r = __half22float2(*reinterpret_cast<const __half2*>(hs + 2LL * s));
        ax += r.x; ay += r.y;
    }
    ax += __shfl_xor(ax, 1); ax += __shfl_xor(ax, 2); ax += __shfl_xor(ax, 4);
    ay += __shfl_xor(ay, 1); ay += __shfl_xor(ay, 2); ay += __shfl_xor(ay, 4);
    if (l8 == 0) {
        float di = dinv[node];
        float a = ax * di + b[0];
        float c = ay * di + b[1];
        float m = fmaxf(a, c);
        float lse = m + logf(expf(a - m) + expf(c - m));
        float2 r = make_float2(a - lse, c - lse);
        *reinterpret_cast<float2*>(out + 2LL * node) = r;
    }
}

static inline int cdiv_ll(long long a, int b) { return (int)((a + b - 1) / b); }
static inline char* align16(char* p) { return (char*)(((uintptr_t)p + 15) & ~(uintptr_t)15); }

extern "C" void kernel_launch(void* const* d_in, const int* in_sizes, int n_in,
                              void* d_out, int out_size, void* d_ws, size_t ws_size,
                              hipStream_t stream) {
    (void)n_in; (void)out_size; (void)ws_size;

    const float* x  = (const float*)d_in[0];      // [N,18]
    const int*   ei = (const int*)d_in[1];        // [2,E]
    const float* W1 = (const float*)d_in[2];
    const float* b1 = (const float*)d_in[3];
    const float* W2 = (const float*)d_in[4];
    const float* b2 = (const float*)d_in[5];
    const float* W3 = (const float*)d_in[6];
    const float* b3 = (const float*)d_in[7];
    const float* W4 = (const float*)d_in[8];
    const float* b4 = (const float*)d_in[9];

    const int n = in_sizes[0] / 18;               // 100000
    const int E = in_sizes[1] / 2;                // 1600000
    const int* src = ei;
    const int* dst = ei + E;
    const int nbuck = (n + 255) >> NBUCK_SHIFT;   // 391

    // ---- workspace layout (16B-aligned regions) ----
    char* p = (char*)d_ws;
    int*    gcur       = (int*)p;            p = align16(p + 512 * 4);
    int2*   ends       = (int2*)p;           p = align16(p + (size_t)n * 8);
    float*  dinv       = (float*)p;          p = align16(p + (size_t)n * 4);
    int*    sorted_src = (int*)p;            p = align16(p + (size_t)nbuck * CAP * 4);  // 12.8MB padded
    unsigned int* bucketed = (unsigned int*)p; p = align16(p + (size_t)nbuck * CAP * 4); // 12.8MB padded
    __half* xs         = (__half*)p;         p = align16(p + (size_t)n * 32 * 2);  // 6.4MB
    __half* h2s        = (__half*)p;         p = align16(p + (size_t)n * 32 * 2);  // 6.4MB
    __half* h3s        = (__half*)p;         p = align16(p + (size_t)n * 16 * 2);  // 3.2MB
    __half* h4s        = (__half*)p;         p = align16(p + (size_t)n * 2 * 2);   // 0.4MB

    const int B = 256;
    const int NODE8_BLOCKS = cdiv_ll(8LL * n, B);

    // ---- CSR-by-dst via fixed-capacity bucketed sort (no hist/scan) ----
    init_gcur_kernel<<<1, 512, 0, stream>>>(gcur, nbuck);
    partition_kernel<<<cdiv_ll(E, PART_CHUNK), B, 0, stream>>>(src, dst, gcur, bucketed, E, nbuck);
    csr_kernel<<<nbuck, B, 0, stream>>>(bucketed, gcur, x, ends, dinv, sorted_src, xs, n);

    // ---- fused pipeline (8 lanes/node, row-split gathers) ----
    layer12_kernel<<<NODE8_BLOCKS, B, 0, stream>>>(xs, dinv, sorted_src, ends, W1, b1, W2, h2s, n);
    layer3_kernel<<<NODE8_BLOCKS, B, 0, stream>>>(h2s, dinv, sorted_src, ends, b2, W3, h3s, n);
    layer4_kernel<<<NODE8_BLOCKS, B, 0, stream>>>(h3s, dinv, sorted_src, ends, b3, W4, h4s, n);
    agg2_lsm_kernel<<<NODE8_BLOCKS, B, 0, stream>>>(h4s, dinv, sorted_src, ends, b4, (float*)d_out, n);
}

// Round 3
// 202.743 us; speedup vs baseline: 1.1921x; 1.1921x over previous
//
#include <hip/hip_runtime.h>
#include <hip/hip_bf16.h>
#include <hip/hip_fp16.h>

// ============================================================================
// GCN forward. CSR-by-dst via fixed-capacity bucketed counting sort; fused
// gather+dense layer kernels, 8 lanes/node, EDGE-SPLIT gathers with 4-WAY
// BATCHED SOFTWARE PIPELINING:
//   - gather: lane l8 handles edges e = be.x+l8, +8, +16, ... Four edges are
//     processed per loop iteration: all 4 index loads issue together, then
//     all 4 row loads together -> ONE latency round for deg <= 32 (99.99% of
//     Poisson(16) nodes) instead of deg/8 serialized rounds. Out-of-range
//     slots clamp to a dedicated ALL-ZERO row at index n (each hs table has
//     n+1 rows), so no divergent guards on the accumulate.
//   - dense: packed-fp16 weights in LDS + v_dot2_f32_f16 (f32 accumulate):
//       * L12 stage-1 (18->64): 9 k-pair dot2s, j-split 8.
//       * L12 stage-2 (64->32): f-split 8, octet shfl exchange, b128 LDS.
//       * L3 (32->16): reduce-scatter -> lane owns 4 k's -> f-split dot2.
//       * L4 (16->2):  reduce-scatter -> lane owns 2 k's.
//   - xs rows padded to 32 halves (64B) so every random gather is exactly
//     one 64B sector; only 36B (2xb128 + b32) actually loaded.
// Algebra: A_hat(xW) = (A_hat x)W, normalization factored as
//   out[d] = dinv[d] * ( sum_{s in N(d)} hs[s] + hs[d] ) + b,  hs = h*dinv[row]
// hs tables fp16 (fp32 accumulation): xs=6.4MB, h2s=6.4MB, h3s=3.2MB.
// ============================================================================

#define NBUCK_SHIFT 8            // 256 nodes per bucket
#define CAP         8192         // bucket capacity (avg 4096, sigma ~64)
#define PART_CHUNK  2048         // edges per partition block (256 thr x 8)

// ---------------- fp16 pair helpers ----------------
typedef _Float16 h2vec __attribute__((ext_vector_type(2)));

__device__ inline unsigned int pack2(float a, float b) {
    __half2 h = __floats2half2_rn(a, b);
    return *reinterpret_cast<unsigned int*>(&h);
}

__device__ inline float2 h2f(unsigned int u) {
    __half2 h = *reinterpret_cast<__half2*>(&u);
    return __half22float2(h);
}

__device__ inline float dot2f(unsigned int w, unsigned int h, float c) {
#if defined(__has_builtin) && __has_builtin(__builtin_amdgcn_fdot2)
    union U { unsigned int u; h2vec v; };
    U uw, uh; uw.u = w; uh.u = h;
    return __builtin_amdgcn_fdot2(uh.v, uw.v, c, false);
#else
    float2 wf = h2f(w);
    float2 hf = h2f(h);
    return fmaf(hf.x, wf.x, fmaf(hf.y, wf.y, c));
#endif
}

// accumulate 8 halves (one uint4) into acc[0..7]
__device__ inline void accq(float* acc, const uint4& r) {
    float2 t;
    t = h2f(r.x); acc[0] += t.x; acc[1] += t.y;
    t = h2f(r.y); acc[2] += t.x; acc[3] += t.y;
    t = h2f(r.z); acc[4] += t.x; acc[5] += t.y;
    t = h2f(r.w); acc[6] += t.x; acc[7] += t.y;
}

// ---------------- init per-bucket cursors to fixed bases ----------------
__global__ void init_gcur_kernel(int* __restrict__ gcur, int nbuck) {
    int i = threadIdx.x;
    if (i < nbuck) gcur[i] = i * CAP;
}

// ---------------- partition edges into fixed-capacity buckets ----------------
// staged word: (src << 8) | (dst & 255)
__global__ __launch_bounds__(256) void partition_kernel(const int* __restrict__ src,
                                                        const int* __restrict__ dst,
                                                        int* __restrict__ gcur,
                                                        unsigned int* __restrict__ bucketed,
                                                        int n_edges, int nbuck) {
    __shared__ int cnt[512];
    __shared__ int base[512];
    const int t = threadIdx.x;
    for (int i = t; i < 512; i += 256) cnt[i] = 0;
    __syncthreads();
    long long start = (long long)blockIdx.x * PART_CHUNK;
    int sv[8], dv[8], bv[8];
#pragma unroll
    for (int k = 0; k < 8; ++k) {
        long long e = start + (long long)k * 256 + t;
        bool ok = e < n_edges;
        sv[k] = ok ? src[e] : 0;
        dv[k] = ok ? dst[e] : 0;
        bv[k] = ok ? (dv[k] >> NBUCK_SHIFT) : -1;
        if (ok) atomicAdd(&cnt[bv[k]], 1);
    }
    __syncthreads();
    for (int i = t; i < nbuck; i += 256) {
        int c = cnt[i];
        base[i] = c ? atomicAdd(&gcur[i], c) : 0;
    }
    __syncthreads();
    for (int i = t; i < 512; i += 256) cnt[i] = 0;   // reuse as running cursor
    __syncthreads();
#pragma unroll
    for (int k = 0; k < 8; ++k) {
        if (bv[k] >= 0) {
            int pos = base[bv[k]] + atomicAdd(&cnt[bv[k]], 1);
            bucketed[pos] = ((unsigned int)sv[k] << 8) | (unsigned int)(dv[k] & 255);
        }
    }
}

// ---------------- per-bucket CSR finalize + x scale/pad ----------------------
// ends=(beg,end), dinv, sorted_src placement, and xs = half(x*dinv) stride 32,
// zero-padded; also zeroes the dummy row xs[n].
__device__ inline float4 pack8_dev(const float* v) {
    float4 out;
    __half2* h2 = reinterpret_cast<__half2*>(&out);
#pragma unroll
    for (int j = 0; j < 4; ++j) h2[j] = __floats2half2_rn(v[2 * j], v[2 * j + 1]);
    return out;
}

__global__ __launch_bounds__(256) void csr_kernel(const unsigned int* __restrict__ bucketed,
                                                  const int* __restrict__ gcur,
                                                  const float* __restrict__ x,
                                                  int2* __restrict__ ends,
                                                  float* __restrict__ dinv,
                                                  int* __restrict__ sorted_src,
                                                  __half* __restrict__ xs,
                                                  int n) {
    __shared__ int ldeg[256];
    __shared__ int lscan[256];
    const int b = blockIdx.x;
    const int t = threadIdx.x;
    const int beg = b * CAP;
    const int end = gcur[b];                 // beg + count(bucket b)
    ldeg[t] = 0;
    __syncthreads();
    for (int e = beg + t; e < end; e += 256) {
        unsigned int p = bucketed[e];
        atomicAdd(&ldeg[p & 255u], 1);
    }
    __syncthreads();
    int v = ldeg[t];
    lscan[t] = v;
    __syncthreads();
    for (int off = 1; off < 256; off <<= 1) {
        int xv = (t >= off) ? lscan[t - off] : 0;
        __syncthreads();
        lscan[t] += xv;
        __syncthreads();
    }
    int excl = lscan[t] - v;                 // exclusive scan
    int node = (b << NBUCK_SHIFT) + t;
    float di = rsqrtf((float)v + 1.0f);      // +1 self-loop
    if (node < n) {
        ends[node] = make_int2(beg + excl, beg + excl + v);
        dinv[node] = di;
        // xs row = half(x * di), stride 32 halves, halves 18..31 zeroed
        const float* xr = x + (long long)node * 18;
        float vv[18];
#pragma unroll
        for (int k = 0; k < 18; ++k) vv[k] = xr[k] * di;
        float vt[8] = {vv[16], vv[17], 0.0f, 0.0f, 0.0f, 0.0f, 0.0f, 0.0f};
        float4* o = reinterpret_cast<float4*>(xs + (long long)node * 32);
        o[0] = pack8_dev(vv);
        o[1] = pack8_dev(vv + 8);
        o[2] = pack8_dev(vt);
        o[3] = make_float4(0.0f, 0.0f, 0.0f, 0.0f);
    }
    if (b == 0 && t == 0) {                  // dummy zero row xs[n]
        float4 z = make_float4(0.0f, 0.0f, 0.0f, 0.0f);
        float4* o = reinterpret_cast<float4*>(xs + (long long)n * 32);
        o[0] = z; o[1] = z; o[2] = z; o[3] = z;
    }
    __syncthreads();
    lscan[t] = beg + excl;                   // reuse as placement cursor
    __syncthreads();
    for (int e = beg + t; e < end; e += 256) {
        unsigned int p = bucketed[e];
        int pos = atomicAdd(&lscan[p & 255u], 1);
        sorted_src[pos] = (int)(p >> 8);
    }
}

// ---------------- fused layer 1+2 (8 lanes/node, batched edge-split) --------
__global__ __launch_bounds__(256) void layer12_kernel(
    const __half* __restrict__ xs, const float* __restrict__ dinv,
    const int* __restrict__ sorted_src, const int2* __restrict__ ends,
    const float* __restrict__ W1, const float* __restrict__ b1,
    const float* __restrict__ W2, __half* __restrict__ h2s, int n) {
    __shared__ unsigned int w1h[9 * 64];     // [kp][j] pairs of x-dim
    __shared__ float sB1[64];
    __shared__ unsigned int w2h[32 * 32];    // [jp][f] pairs of hidden-dim
    for (int i = threadIdx.x; i < 9 * 64; i += 256) {
        int kp = i >> 6, j = i & 63;
        w1h[i] = pack2(W1[(2 * kp) * 64 + j], W1[(2 * kp + 1) * 64 + j]);
    }
    for (int i = threadIdx.x; i < 64; i += 256) sB1[i] = b1[i];
    for (int i = threadIdx.x; i < 32 * 32; i += 256) {
        int jp = i >> 5, f = i & 31;
        w2h[i] = pack2(W2[(2 * jp) * 32 + f], W2[(2 * jp + 1) * 32 + f]);
    }
    __syncthreads();

    long long gt = (long long)blockIdx.x * 256 + threadIdx.x;
    int node = (int)(gt >> 3);
    int l8   = (int)(gt & 7);
    if (node >= n) return;
    int2 be = ends[node];
    float di = dinv[node];

    // ---- gather: 4-way batched edge-split; dummy slots -> zero row n ----
    float acc[18];
#pragma unroll
    for (int j = 0; j < 18; ++j) acc[j] = 0.0f;
    if (l8 == 7) {   // self row
        const __half* p = xs + ((long long)node << 5);
        uint4 ra = *reinterpret_cast<const uint4*>(p);
        uint4 rb = *reinterpret_cast<const uint4*>(p + 8);
        unsigned int rc = *reinterpret_cast<const unsigned int*>(p + 16);
        accq(acc, ra); accq(acc + 8, rb);
        float2 t = h2f(rc); acc[16] += t.x; acc[17] += t.y;
    }
    const int last = be.y - 1;
    for (int e = be.x + l8; e < be.y; e += 32) {
        int i1 = e + 8, i2 = e + 16, i3 = e + 24;
        int s0 = sorted_src[e];
        int v1 = sorted_src[i1 <= last ? i1 : last];
        int v2 = sorted_src[i2 <= last ? i2 : last];
        int v3 = sorted_src[i3 <= last ? i3 : last];
        int s1 = (i1 <= last) ? v1 : n;
        int s2 = (i2 <= last) ? v2 : n;
        int s3 = (i3 <= last) ? v3 : n;
        const __half* p0 = xs + ((long long)s0 << 5);
        const __half* p1 = xs + ((long long)s1 << 5);
        const __half* p2 = xs + ((long long)s2 << 5);
        const __half* p3 = xs + ((long long)s3 << 5);
        uint4 r0a = *reinterpret_cast<const uint4*>(p0);
        uint4 r0b = *reinterpret_cast<const uint4*>(p0 + 8);
        unsigned int r0c = *reinterpret_cast<const unsigned int*>(p0 + 16);
        uint4 r1a = *reinterpret_cast<const uint4*>(p1);
        uint4 r1b = *reinterpret_cast<const uint4*>(p1 + 8);
        unsigned int r1c = *reinterpret_cast<const unsigned int*>(p1 + 16);
        uint4 r2a = *reinterpret_cast<const uint4*>(p2);
        uint4 r2b = *reinterpret_cast<const uint4*>(p2 + 8);
        unsigned int r2c = *reinterpret_cast<const unsigned int*>(p2 + 16);
        uint4 r3a = *reinterpret_cast<const uint4*>(p3);
        uint4 r3b = *reinterpret_cast<const uint4*>(p3 + 8);
        unsigned int r3c = *reinterpret_cast<const unsigned int*>(p3 + 16);
        float2 t;
        accq(acc, r0a); accq(acc + 8, r0b); t = h2f(r0c); acc[16] += t.x; acc[17] += t.y;
        accq(acc, r1a); accq(acc + 8, r1b); t = h2f(r1c); acc[16] += t.x; acc[17] += t.y;
        accq(acc, r2a); accq(acc + 8, r2b); t = h2f(r2c); acc[16] += t.x; acc[17] += t.y;
        accq(acc, r3a); accq(acc + 8, r3b); t = h2f(r3c); acc[16] += t.x; acc[17] += t.y;
    }
#pragma unroll
    for (int j = 0; j < 18; ++j) {       // all-reduce over octet (di folded later)
        acc[j] += __shfl_xor(acc[j], 1);
        acc[j] += __shfl_xor(acc[j], 2);
        acc[j] += __shfl_xor(acc[j], 4);
    }
    unsigned int ap[9];
#pragma unroll
    for (int q = 0; q < 9; ++q) ap[q] = pack2(acc[2 * q], acc[2 * q + 1]);

    // ---- stage 1: hidden slice j0 = l8*8, dot2 over 9 k-pairs ----
    const int j0 = l8 * 8;
    float raw[8];
#pragma unroll
    for (int jj = 0; jj < 8; ++jj) raw[jj] = 0.0f;
#pragma unroll
    for (int kp = 0; kp < 9; ++kp) {
        const uint4* wv = reinterpret_cast<const uint4*>(&w1h[kp * 64 + j0]);
        uint4 wa = wv[0], wb = wv[1];
        unsigned int a = ap[kp];
        raw[0] = dot2f(wa.x, a, raw[0]); raw[1] = dot2f(wa.y, a, raw[1]);
        raw[2] = dot2f(wa.z, a, raw[2]); raw[3] = dot2f(wa.w, a, raw[3]);
        raw[4] = dot2f(wb.x, a, raw[4]); raw[5] = dot2f(wb.y, a, raw[5]);
        raw[6] = dot2f(wb.z, a, raw[6]); raw[7] = dot2f(wb.w, a, raw[7]);
    }
    unsigned int hpu[4];
#pragma unroll
    for (int q = 0; q < 4; ++q) {          // hid = relu(di*raw + b1), packed
        float h0 = fmaxf(fmaf(raw[2 * q],     di, sB1[j0 + 2 * q]),     0.0f);
        float h1 = fmaxf(fmaf(raw[2 * q + 1], di, sB1[j0 + 2 * q + 1]), 0.0f);
        hpu[q] = pack2(h0, h1);
    }

    // ---- stage 2: f-split (f0 = l8*4); hid pairs exchanged via octet shfl --
    float out[4] = {0.0f, 0.0f, 0.0f, 0.0f};
#pragma unroll
    for (int m = 0; m < 8; ++m) {
        const int lx = l8 ^ m;
#pragma unroll
        for (int q = 0; q < 4; ++q) {
            unsigned int hh = m ? (unsigned int)__shfl_xor(hpu[q], m) : hpu[q];
            const uint4 w = *reinterpret_cast<const uint4*>(&w2h[(lx * 4 + q) * 32 + l8 * 4]);
            out[0] = dot2f(w.x, hh, out[0]);
            out[1] = dot2f(w.y, hh, out[1]);
            out[2] = dot2f(w.z, hh, out[2]);
            out[3] = dot2f(w.w, hh, out[3]);
        }
    }
    union { float2 f2; __half2 h2[2]; } u;
    u.h2[0] = __floats2half2_rn(out[0] * di, out[1] * di);
    u.h2[1] = __floats2half2_rn(out[2] * di, out[3] * di);
    *reinterpret_cast<float2*>(h2s + (long long)node * 32 + l8 * 4) = u.f2;
    if (node == 0)                           // dummy zero row h2s[n]
        *reinterpret_cast<float2*>(h2s + (long long)n * 32 + l8 * 4) = make_float2(0.0f, 0.0f);
}

// ---------------- fused layer 3 (8 lanes/node, batched edge-split) ----------
__global__ __launch_bounds__(256) void layer3_kernel(
    const __half* __restrict__ h2s, const float* __restrict__ dinv,
    const int* __restrict__ sorted_src, const int2* __restrict__ ends,
    const float* __restrict__ b2, const float* __restrict__ W3,
    __half* __restrict__ h3s, int n) {
    __shared__ unsigned int w3h[16 * 16];    // [kp][f] pairs of k-dim
    __shared__ float sB2[32];
    {
        int i = threadIdx.x;
        if (i < 256) {
            int kp = i >> 4, f = i & 15;
            w3h[i] = pack2(W3[(2 * kp) * 16 + f], W3[(2 * kp + 1) * 16 + f]);
        }
    }
    for (int i = threadIdx.x; i < 32; i += 256) sB2[i] = b2[i];
    __syncthreads();

    long long gt = (long long)blockIdx.x * 256 + threadIdx.x;
    int node = (int)(gt >> 3);
    int l8   = (int)(gt & 7);
    if (node >= n) return;
    int2 be = ends[node];
    float di = dinv[node];

    float acc[32];
#pragma unroll
    for (int j = 0; j < 32; ++j) acc[j] = 0.0f;
    if (l8 == 7) {
        const uint4* pp = reinterpret_cast<const uint4*>(h2s + ((long long)node << 5));
        accq(acc, pp[0]); accq(acc + 8, pp[1]); accq(acc + 16, pp[2]); accq(acc + 24, pp[3]);
    }
    const int last = be.y - 1;
    for (int e = be.x + l8; e < be.y; e += 32) {
        int i1 = e + 8, i2 = e + 16, i3 = e + 24;
        int s0 = sorted_src[e];
        int v1 = sorted_src[i1 <= last ? i1 : last];
        int v2 = sorted_src[i2 <= last ? i2 : last];
        int v3 = sorted_src[i3 <= last ? i3 : last];
        int s1 = (i1 <= last) ? v1 : n;
        int s2 = (i2 <= last) ? v2 : n;
        int s3 = (i3 <= last) ? v3 : n;
        const uint4* p0 = reinterpret_cast<const uint4*>(h2s + ((long long)s0 << 5));
        const uint4* p1 = reinterpret_cast<const uint4*>(h2s + ((long long)s1 << 5));
        const uint4* p2 = reinterpret_cast<const uint4*>(h2s + ((long long)s2 << 5));
        const uint4* p3 = reinterpret_cast<const uint4*>(h2s + ((long long)s3 << 5));
        uint4 r00 = p0[0], r01 = p0[1], r02 = p0[2], r03 = p0[3];
        uint4 r10 = p1[0], r11 = p1[1], r12 = p1[2], r13 = p1[3];
        uint4 r20 = p2[0], r21 = p2[1], r22 = p2[2], r23 = p2[3];
        uint4 r30 = p3[0], r31 = p3[1], r32 = p3[2], r33 = p3[3];
        accq(acc, r00); accq(acc + 8, r01); accq(acc + 16, r02); accq(acc + 24, r03);
        accq(acc, r10); accq(acc + 8, r11); accq(acc + 16, r12); accq(acc + 24, r13);
        accq(acc, r20); accq(acc + 8, r21); accq(acc + 16, r22); accq(acc + 24, r23);
        accq(acc, r30); accq(acc + 8, r31); accq(acc + 16, r32); accq(acc + 24, r33);
    }
    // reduce-scatter acc[32] over octet -> lane owns k in [4*l8, 4*l8+4)
    const bool hi4 = (l8 & 4);
    float h16[16];
#pragma unroll
    for (int v = 0; v < 16; ++v) {
        float keep = hi4 ? acc[16 + v] : acc[v];
        float send = hi4 ? acc[v] : acc[16 + v];
        h16[v] = keep + __shfl_xor(send, 4);
    }
    const bool hi2 = (l8 & 2);
    float h8[8];
#pragma unroll
    for (int v = 0; v < 8; ++v) {
        float keep = hi2 ? h16[8 + v] : h16[v];
        float send = hi2 ? h16[v] : h16[8 + v];
        h8[v] = keep + __shfl_xor(send, 2);
    }
    const bool hi1 = (l8 & 1);
    float k4[4];
#pragma unroll
    for (int v = 0; v < 4; ++v) {
        float keep = hi1 ? h8[4 + v] : h8[v];
        float send = hi1 ? h8[v] : h8[4 + v];
        k4[v] = keep + __shfl_xor(send, 1);
    }

    // ---- dense: relu'd k-pairs exchanged via octet shfl, dot2 ----
    const int k0 = l8 * 4;
    float v0 = fmaxf(fmaf(k4[0], di, sB2[k0 + 0]), 0.0f);
    float v1 = fmaxf(fmaf(k4[1], di, sB2[k0 + 1]), 0.0f);
    float v2 = fmaxf(fmaf(k4[2], di, sB2[k0 + 2]), 0.0f);
    float v3 = fmaxf(fmaf(k4[3], di, sB2[k0 + 3]), 0.0f);
    unsigned int vp[2] = { pack2(v0, v1), pack2(v2, v3) };
    float o0 = 0.0f, o1 = 0.0f;
#pragma unroll
    for (int m = 0; m < 8; ++m) {
        const int lx = l8 ^ m;
#pragma unroll
        for (int q = 0; q < 2; ++q) {
            unsigned int hh = m ? (unsigned int)__shfl_xor(vp[q], m) : vp[q];
            const uint2 w = *reinterpret_cast<const uint2*>(&w3h[(lx * 2 + q) * 16 + l8 * 2]);
            o0 = dot2f(w.x, hh, o0);
            o1 = dot2f(w.y, hh, o1);
        }
    }
    *reinterpret_cast<__half2*>(h3s + (long long)node * 16 + l8 * 2) =
        __floats2half2_rn(o0 * di, o1 * di);
    if (node == 0)                           // dummy zero row h3s[n]
        *reinterpret_cast<__half2*>(h3s + (long long)n * 16 + l8 * 2) =
            __floats2half2_rn(0.0f, 0.0f);
}

// ---------------- fused layer 4 (8 lanes/node, batched edge-split) -----------
__global__ __launch_bounds__(256) void layer4_kernel(
    const __half* __restrict__ h3s, const float* __restrict__ dinv,
    const int* __restrict__ sorted_src, const int2* __restrict__ ends,
    const float* __restrict__ b3, const float* __restrict__ W4,
    __half* __restrict__ h4s, int n) {
    __shared__ float sW4[32];
    __shared__ float sB3[16];
    for (int i = threadIdx.x; i < 32; i += 256) sW4[i] = W4[i];
    for (int i = threadIdx.x; i < 16; i += 256) sB3[i] = b3[i];
    __syncthreads();

    long long gt = (long long)blockIdx.x * 256 + threadIdx.x;
    int node = (int)(gt >> 3);
    int l8   = (int)(gt & 7);
    if (node >= n) return;
    int2 be = ends[node];
    float di = dinv[node];

    float acc[16];
#pragma unroll
    for (int j = 0; j < 16; ++j) acc[j] = 0.0f;
    if (l8 == 7) {
        const uint4* pp = reinterpret_cast<const uint4*>(h3s + ((long long)node << 4));
        accq(acc, pp[0]); accq(acc + 8, pp[1]);
    }
    const int last = be.y - 1;
    for (int e = be.x + l8; e < be.y; e += 32) {
        int i1 = e + 8, i2 = e + 16, i3 = e + 24;
        int s0 = sorted_src[e];
        int v1 = sorted_src[i1 <= last ? i1 : last];
        int v2 = sorted_src[i2 <= last ? i2 : last];
        int v3 = sorted_src[i3 <= last ? i3 : last];
        int s1 = (i1 <= last) ? v1 : n;
        int s2 = (i2 <= last) ? v2 : n;
        int s3 = (i3 <= last) ? v3 : n;
        const uint4* p0 = reinterpret_cast<const uint4*>(h3s + ((long long)s0 << 4));
        const uint4* p1 = reinterpret_cast<const uint4*>(h3s + ((long long)s1 << 4));
        const uint4* p2 = reinterpret_cast<const uint4*>(h3s + ((long long)s2 << 4));
        const uint4* p3 = reinterpret_cast<const uint4*>(h3s + ((long long)s3 << 4));
        uint4 r00 = p0[0], r01 = p0[1];
        uint4 r10 = p1[0], r11 = p1[1];
        uint4 r20 = p2[0], r21 = p2[1];
        uint4 r30 = p3[0], r31 = p3[1];
        accq(acc, r00); accq(acc + 8, r01);
        accq(acc, r10); accq(acc + 8, r11);
        accq(acc, r20); accq(acc + 8, r21);
        accq(acc, r30); accq(acc + 8, r31);
    }
    // reduce-scatter acc[16] over octet -> lane owns k in [2*l8, 2*l8+2)
    const bool hi4 = (l8 & 4);
    float h8[8];
#pragma unroll
    for (int v = 0; v < 8; ++v) {
        float keep = hi4 ? acc[8 + v] : acc[v];
        float send = hi4 ? acc[v] : acc[8 + v];
        h8[v] = keep + __shfl_xor(send, 4);
    }
    const bool hi2 = (l8 & 2);
    float h4v[4];
#pragma unroll
    for (int v = 0; v < 4; ++v) {
        float keep = hi2 ? h8[4 + v] : h8[v];
        float send = hi2 ? h8[v] : h8[4 + v];
        h4v[v] = keep + __shfl_xor(send, 2);
    }
    const bool hi1 = (l8 & 1);
    float k2[2];
#pragma unroll
    for (int v = 0; v < 2; ++v) {
        float keep = hi1 ? h4v[2 + v] : h4v[v];
        float send = hi1 ? h4v[v] : h4v[2 + v];
        k2[v] = keep + __shfl_xor(send, 1);
    }
    const int k0 = l8 * 2;
    float o0 = 0.0f, o1 = 0.0f;
#pragma unroll
    for (int kk = 0; kk < 2; ++kk) {
        float v = fmaxf(fmaf(k2[kk], di, sB3[k0 + kk]), 0.0f);
        o0 = fmaf(v, sW4[2 * (k0 + kk)], o0);
        o1 = fmaf(v, sW4[2 * (k0 + kk) + 1], o1);
    }
    o0 += __shfl_xor(o0, 1); o0 += __shfl_xor(o0, 2); o0 += __shfl_xor(o0, 4);
    o1 += __shfl_xor(o1, 1); o1 += __shfl_xor(o1, 2); o1 += __shfl_xor(o1, 4);
    if (l8 == 0) {
        *reinterpret_cast<__half2*>(h4s + 2LL * node) = __floats2half2_rn(o0 * di, o1 * di);
        if (node == 0)                       // dummy zero row h4s[n]
            *reinterpret_cast<__half2*>(h4s + 2LL * n) = __floats2half2_rn(0.0f, 0.0f);
    }
}

// ---------------- final: F=2 aggregation + log_softmax (8 lanes/node) --------
__global__ __launch_bounds__(256) void agg2_lsm_kernel(
    const __half* __restrict__ hs, const float* __restrict__ dinv,
    const int* __restrict__ sorted_src, const int2* __restrict__ ends,
    const float* __restrict__ b, float* __restrict__ out, int n) {
    long long gt = (long long)blockIdx.x * 256 + threadIdx.x;
    int node = (int)(gt >> 3);
    int l8   = (int)(gt & 7);
    if (node >= n) return;
    int2 be = ends[node];
    float ax = 0.0f, ay = 0.0f;
    if (l8 == 7) {
        float2 r = __half22float2(*reinterpret_cast<const __half2*>(hs + 2LL * node));
        ax += r.x; ay += r.y;
    }
    const int last = be.y - 1;
    for (int e = be.x + l8; e < be.y; e += 32) {
        int i1 = e + 8, i2 = e + 16, i3 = e + 24;
        int s0 = sorted_src[e];
        int v1 = sorted_src[i1 <= last ? i1 : last];
        int v2 = sorted_src[i2 <= last ? i2 : last];
        int v3 = sorted_src[i3 <= last ? i3 : last];
        int s1 = (i1 <= last) ? v1 : n;
        int s2 = (i2 <= last) ? v2 : n;
        int s3 = (i3 <= last) ? v3 : n;
        unsigned int r0 = *reinterpret_cast<const unsigned int*>(hs + 2LL * s0);
        unsigned int r1 = *reinterpret_cast<const unsigned int*>(hs + 2LL * s1);
        unsigned int r2 = *reinterpret_cast<const unsigned int*>(hs + 2LL * s2);
        unsigned int r3 = *reinterpret_cast<const unsigned int*>(hs + 2LL * s3);
        float2 t;
        t = h2f(r0); ax += t.x; ay += t.y;
        t = h2f(r1); ax += t.x; ay += t.y;
        t = h2f(r2); ax += t.x; ay += t.y;
        t = h2f(r3); ax += t.x; ay += t.y;
    }
    ax += __shfl_xor(ax, 1); ax += __shfl_xor(ax, 2); ax += __shfl_xor(ax, 4);
    ay += __shfl_xor(ay, 1); ay += __shfl_xor(ay, 2); ay += __shfl_xor(ay, 4);
    if (l8 == 0) {
        float di = dinv[node];
        float a = ax * di + b[0];
        float c = ay * di + b[1];
        float m = fmaxf(a, c);
        float lse = m + logf(expf(a - m) + expf(c - m));
        float2 r = make_float2(a - lse, c - lse);
        *reinterpret_cast<float2*>(out + 2LL * node) = r;
    }
}

static inline int cdiv_ll(long long a, int b) { return (int)((a + b - 1) / b); }
static inline char* align16(char* p) { return (char*)(((uintptr_t)p + 15) & ~(uintptr_t)15); }

extern "C" void kernel_launch(void* const* d_in, const int* in_sizes, int n_in,
                              void* d_out, int out_size, void* d_ws, size_t ws_size,
                              hipStream_t stream) {
    (void)n_in; (void)out_size; (void)ws_size;

    const float* x  = (const float*)d_in[0];      // [N,18]
    const int*   ei = (const int*)d_in[1];        // [2,E]
    const float* W1 = (const float*)d_in[2];
    const float* b1 = (const float*)d_in[3];
    const float* W2 = (const float*)d_in[4];
    const float* b2 = (const float*)d_in[5];
    const float* W3 = (const float*)d_in[6];
    const float* b3 = (const float*)d_in[7];
    const float* W4 = (const float*)d_in[8];
    const float* b4 = (const float*)d_in[9];

    const int n = in_sizes[0] / 18;               // 100000
    const int E = in_sizes[1] / 2;                // 1600000
    const int* src = ei;
    const int* dst = ei + E;
    const int nbuck = (n + 255) >> NBUCK_SHIFT;   // 391

    // ---- workspace layout (16B-aligned regions; hs tables have n+1 rows) ----
    char* p = (char*)d_ws;
    int*    gcur       = (int*)p;            p = align16(p + 512 * 4);
    int2*   ends       = (int2*)p;           p = align16(p + (size_t)n * 8);
    float*  dinv       = (float*)p;          p = align16(p + (size_t)n * 4);
    int*    sorted_src = (int*)p;            p = align16(p + (size_t)nbuck * CAP * 4);  // 12.8MB padded
    unsigned int* bucketed = (unsigned int*)p; p = align16(p + (size_t)nbuck * CAP * 4); // 12.8MB padded
    __half* xs         = (__half*)p;         p = align16(p + (size_t)(n + 1) * 32 * 2);  // 6.4MB
    __half* h2s        = (__half*)p;         p = align16(p + (size_t)(n + 1) * 32 * 2);  // 6.4MB
    __half* h3s        = (__half*)p;         p = align16(p + (size_t)(n + 1) * 16 * 2);  // 3.2MB
    __half* h4s        = (__half*)p;         p = align16(p + (size_t)(n + 1) * 2 * 2);   // 0.4MB

    const int B = 256;
    const int NODE8_BLOCKS = cdiv_ll(8LL * n, B);

    // ---- CSR-by-dst via fixed-capacity bucketed sort (no hist/scan) ----
    init_gcur_kernel<<<1, 512, 0, stream>>>(gcur, nbuck);
    partition_kernel<<<cdiv_ll(E, PART_CHUNK), B, 0, stream>>>(src, dst, gcur, bucketed, E, nbuck);
    csr_kernel<<<nbuck, B, 0, stream>>>(bucketed, gcur, x, ends, dinv, sorted_src, xs, n);

    // ---- fused pipeline (8 lanes/node, batched edge-split gathers) ----
    layer12_kernel<<<NODE8_BLOCKS, B, 0, stream>>>(xs, dinv, sorted_src, ends, W1, b1, W2, h2s, n);
    layer3_kernel<<<NODE8_BLOCKS, B, 0, stream>>>(h2s, dinv, sorted_src, ends, b2, W3, h3s, n);
    layer4_kernel<<<NODE8_BLOCKS, B, 0, stream>>>(h3s, dinv, sorted_src, ends, b3, W4, h4s, n);
    agg2_lsm_kernel<<<NODE8_BLOCKS, B, 0, stream>>>(h4s, dinv, sorted_src, ends, b4, (float*)d_out, n);
}